// Round 1
// baseline (274.231 us; speedup 1.0000x reference)
//
#include <hip/hip_runtime.h>

using short8 = __attribute__((ext_vector_type(8))) short;
using f32x4  = __attribute__((ext_vector_type(4))) float;

__device__ __forceinline__ unsigned short f2bf(float f) {
  unsigned u = __builtin_bit_cast(unsigned, f);
  return (unsigned short)((u + 0x7FFFu + ((u >> 16) & 1u)) >> 16);
}

__device__ __forceinline__ short8 pack8(float4 a, float4 b) {
  short8 r;
  r[0] = (short)f2bf(a.x); r[1] = (short)f2bf(a.y);
  r[2] = (short)f2bf(a.z); r[3] = (short)f2bf(a.w);
  r[4] = (short)f2bf(b.x); r[5] = (short)f2bf(b.y);
  r[6] = (short)f2bf(b.z); r[7] = (short)f2bf(b.w);
  return r;
}

// Kernel 1: w = softmax(weight_mat / softplus(tau), axis=-1), one block per row.
__global__ __launch_bounds__(256) void w_softmax_kernel(
    const float* __restrict__ wm, const float* __restrict__ tau,
    float* __restrict__ wout) {
  const int row = blockIdx.x;
  const int tid = threadIdx.x;
  const float sp  = log1pf(__expf(tau[row]));
  const float inv = 1.0f / sp;
  const float* src = wm + (size_t)row * 1024;
  float v0 = src[tid] * inv;
  float v1 = src[tid + 256] * inv;
  float v2 = src[tid + 512] * inv;
  float v3 = src[tid + 768] * inv;
  float mx = fmaxf(fmaxf(v0, v1), fmaxf(v2, v3));
  #pragma unroll
  for (int m = 1; m < 64; m <<= 1) mx = fmaxf(mx, __shfl_xor(mx, m));
  __shared__ float red[8];
  const int wv = tid >> 6;
  if ((tid & 63) == 0) red[wv] = mx;
  __syncthreads();
  mx = fmaxf(fmaxf(red[0], red[1]), fmaxf(red[2], red[3]));
  float e0 = __expf(v0 - mx), e1 = __expf(v1 - mx);
  float e2 = __expf(v2 - mx), e3 = __expf(v3 - mx);
  float s = e0 + e1 + e2 + e3;
  #pragma unroll
  for (int m = 1; m < 64; m <<= 1) s += __shfl_xor(s, m);
  if ((tid & 63) == 0) red[4 + wv] = s;
  __syncthreads();
  s = red[4] + red[5] + red[6] + red[7];
  const float r = 1.0f / s;
  float* dst = wout + (size_t)row * 1024;
  dst[tid]       = e0 * r;
  dst[tid + 256] = e1 * r;
  dst[tid + 512] = e2 * r;
  dst[tid + 768] = e3 * r;
}

// Kernel 2: flash attention with per-(q,s) multiplicative modulation w.
// Block = 256 threads (4 waves), each block: one (b,h) and 64 q rows.
// Wave wv owns q rows [q0+wv*16, +16). KV tiles of 64.
__global__ __launch_bounds__(256) void attn_kernel(
    const float* __restrict__ Q, const float* __restrict__ K,
    const float* __restrict__ V, const float* __restrict__ W,
    float* __restrict__ O) {
  const int bid = blockIdx.x;
  const int qt = bid & 15;        // q-tile fastest: consecutive blocks share K/V
  const int h  = (bid >> 4) & 7;
  const int b  = bid >> 7;
  const int q0 = qt * 64;

  const int tid  = threadIdx.x;
  const int wv   = tid >> 6;
  const int lane = tid & 63;
  const int lc   = lane & 15;
  const int g    = lane >> 4;

  __shared__ alignas(16) short Ks[64 * 64];   // K tile, row s, bf16, XOR-swizzled
  __shared__ alignas(16) short Vt[64 * 64];   // V^T tile, row d, bf16, XOR-swizzled
  __shared__ alignas(16) short Pl[4 * 1152];  // per-wave P (16 x 72 stride)

  // Q A-fragments: m = lc (q row), k = kstep*32 + g*8 + i
  const int qg_frag = q0 + wv * 16 + lc;
  const float* qptr = Q + ((size_t)(b * 1024 + qg_frag)) * 512 + h * 64;
  short8 aQ[2];
  #pragma unroll
  for (int ks = 0; ks < 2; ++ks) {
    float4 f0 = *(const float4*)(qptr + ks * 32 + g * 8);
    float4 f1 = *(const float4*)(qptr + ks * 32 + g * 8 + 4);
    aQ[ks] = pack8(f0, f1);
  }

  // staging assignment: 4 threads per row, 16 contiguous floats each
  const int s_loc = tid >> 2;        // 0..63
  const int cb    = (tid & 3) * 16;  // 0,16,32,48

  f32x4 o[4];
  #pragma unroll
  for (int n = 0; n < 4; ++n) o[n] = (f32x4){0.f, 0.f, 0.f, 0.f};
  float m_r[4] = {-INFINITY, -INFINITY, -INFINITY, -INFINITY};
  float l_r[4] = {0.f, 0.f, 0.f, 0.f};

  // w base: rows q0+wv*16+g*4+r, col lc
  const float* wbase = W + (size_t)(q0 + wv * 16 + g * 4) * 1024 + lc;

  for (int kt = 0; kt < 16; ++kt) {
    const int s0 = kt * 64;
    __syncthreads();  // previous tile fully consumed
    {   // stage K tile -> bf16 LDS, swizzled
      const float* kp = K + ((size_t)(b * 1024 + s0 + s_loc)) * 512 + h * 64 + cb;
      float4 x0 = *(const float4*)(kp);
      float4 x1 = *(const float4*)(kp + 4);
      float4 x2 = *(const float4*)(kp + 8);
      float4 x3 = *(const float4*)(kp + 12);
      const int sw = (s_loc & 7) << 4;
      char* kb = (char*)Ks + s_loc * 128;
      *(short8*)(kb + ((cb * 2) ^ sw))      = pack8(x0, x1);
      *(short8*)(kb + ((cb * 2 + 16) ^ sw)) = pack8(x2, x3);
    }
    {   // stage V tile transposed -> Vt[d][s], swizzled (scalar b16 writes)
      const float* vp = V + ((size_t)(b * 1024 + s0 + s_loc)) * 512 + h * 64 + cb;
      float4 y0 = *(const float4*)(vp);
      float4 y1 = *(const float4*)(vp + 4);
      float4 y2 = *(const float4*)(vp + 8);
      float4 y3 = *(const float4*)(vp + 12);
      float va[16] = {y0.x, y0.y, y0.z, y0.w, y1.x, y1.y, y1.z, y1.w,
                      y2.x, y2.y, y2.z, y2.w, y3.x, y3.y, y3.z, y3.w};
      #pragma unroll
      for (int j = 0; j < 16; ++j) {
        const int d = cb + j;
        const int byte = d * 128 + ((s_loc * 2) ^ ((d & 7) << 4));
        *(short*)((char*)Vt + byte) = (short)f2bf(va[j]);
      }
    }
    __syncthreads();

    // ---- S = Q K^T (per wave: 16 q x 64 s) ----
    f32x4 sacc[4];
    #pragma unroll
    for (int n = 0; n < 4; ++n) {
      const int srow = n * 16 + lc;
      const int swz  = (srow & 7) << 4;
      const char* kb = (const char*)Ks + srow * 128;
      short8 b0 = *(const short8*)(kb + ((g * 16) ^ swz));
      short8 b1 = *(const short8*)(kb + ((64 + g * 16) ^ swz));
      f32x4 z = (f32x4){0.f, 0.f, 0.f, 0.f};
      z = __builtin_amdgcn_mfma_f32_16x16x32_bf16(aQ[0], b0, z, 0, 0, 0);
      z = __builtin_amdgcn_mfma_f32_16x16x32_bf16(aQ[1], b1, z, 0, 0, 0);
      sacc[n] = z;
    }

    // ---- modulation + online softmax (rows g*4+r across 16 lanes lc) ----
    float p[4][4];
    #pragma unroll
    for (int r = 0; r < 4; ++r) {
      float lg[4];
      #pragma unroll
      for (int n = 0; n < 4; ++n) {
        const float wval = wbase[(size_t)r * 1024 + s0 + n * 16];
        lg[n] = sacc[n][r] * 0.125f * wval;
      }
      float tmax = fmaxf(fmaxf(lg[0], lg[1]), fmaxf(lg[2], lg[3]));
      #pragma unroll
      for (int msk = 1; msk < 16; msk <<= 1)
        tmax = fmaxf(tmax, __shfl_xor(tmax, msk));
      const float mnew = fmaxf(m_r[r], tmax);
      const float corr = __expf(m_r[r] - mnew);
      m_r[r] = mnew;
      float rs = 0.f;
      #pragma unroll
      for (int n = 0; n < 4; ++n) {
        p[n][r] = __expf(lg[n] - mnew);
        rs += p[n][r];
      }
      #pragma unroll
      for (int msk = 1; msk < 16; msk <<= 1) rs += __shfl_xor(rs, msk);
      l_r[r] = l_r[r] * corr + rs;
      #pragma unroll
      for (int n = 0; n < 4; ++n) o[n][r] *= corr;
    }

    // ---- P -> per-wave LDS (bf16), then PV ----
    short* pw = Pl + wv * 1152;
    #pragma unroll
    for (int r = 0; r < 4; ++r) {
      #pragma unroll
      for (int n = 0; n < 4; ++n)
        pw[(g * 4 + r) * 72 + n * 16 + lc] = (short)f2bf(p[n][r]);
    }

    const char* pb = (const char*)Pl + wv * 2304 + lc * 144;
    short8 aP0 = *(const short8*)(pb + g * 16);
    short8 aP1 = *(const short8*)(pb + 64 + g * 16);
    #pragma unroll
    for (int n = 0; n < 4; ++n) {
      const int drow = n * 16 + lc;
      const int swz  = (drow & 7) << 4;
      const char* vb = (const char*)Vt + drow * 128;
      short8 b0 = *(const short8*)(vb + ((g * 16) ^ swz));
      short8 b1 = *(const short8*)(vb + ((64 + g * 16) ^ swz));
      o[n] = __builtin_amdgcn_mfma_f32_16x16x32_bf16(aP0, b0, o[n], 0, 0, 0);
      o[n] = __builtin_amdgcn_mfma_f32_16x16x32_bf16(aP1, b1, o[n], 0, 0, 0);
    }
  }

  // ---- epilogue: O / l ----
  #pragma unroll
  for (int r = 0; r < 4; ++r) {
    const float invl = 1.0f / l_r[r];
    const int qg = q0 + wv * 16 + g * 4 + r;
    float* op = O + ((size_t)(b * 1024 + qg)) * 512 + h * 64 + lc;
    #pragma unroll
    for (int n = 0; n < 4; ++n) op[n * 16] = o[n][r] * invl;
  }
}

extern "C" void kernel_launch(void* const* d_in, const int* in_sizes, int n_in,
                              void* d_out, int out_size, void* d_ws, size_t ws_size,
                              hipStream_t stream) {
  const float* Q   = (const float*)d_in[0];
  const float* K   = (const float*)d_in[1];
  const float* V   = (const float*)d_in[2];
  const float* WM  = (const float*)d_in[3];
  const float* TAU = (const float*)d_in[4];
  float* Wbuf = (float*)d_ws;           // 1024*1024*4 = 4 MB scratch
  float* out  = (float*)d_out;

  w_softmax_kernel<<<dim3(1024), dim3(256), 0, stream>>>(WM, TAU, Wbuf);
  attn_kernel<<<dim3(16 * 8 * 16), dim3(256), 0, stream>>>(Q, K, V, Wbuf, out);
}